// Round 1
// baseline (108.477 us; speedup 1.0000x reference)
//
#include <hip/hip_runtime.h>
#include <math.h>

// Problem constants (Spline_Fitting): B=2, S=128, D=256, H=8, E=32
constexpr int BB = 2;
constexpr int SS = 128;
constexpr int DD = 256;
constexpr int HH = 8;
constexpr int EE = 32;

// ---------------------------------------------------------------------------
// K1: x[bh][s][e] = softmax_over_E( inputs @ w_in^T + b_in ), split per head.
// One block per (b,s) row. 256 threads, thread e computes output feature e.
// ---------------------------------------------------------------------------
__global__ __launch_bounds__(256) void spline_k1(
    const float* __restrict__ inp,   // (B,S,D)
    const float* __restrict__ w_in,  // (D,D) row-major, x[e] = sum_d inp[d]*w_in[e*D+d]
    const float* __restrict__ b_in,  // (D,)
    float* __restrict__ xs_out)      // (B*H, S, E)
{
  const int row = blockIdx.x;        // b*S + s
  const int e = threadIdx.x;         // 0..255
  __shared__ float in_row[DD];
  __shared__ float vals[DD];
  __shared__ float exps[DD];

  in_row[e] = inp[row * DD + e];
  __syncthreads();

  const float* wr = w_in + e * DD;
  float acc = b_in[e];
#pragma unroll 8
  for (int d = 0; d < DD; d += 4) {
    const float4 w4 = *reinterpret_cast<const float4*>(wr + d);
    acc = fmaf(in_row[d + 0], w4.x, acc);
    acc = fmaf(in_row[d + 1], w4.y, acc);
    acc = fmaf(in_row[d + 2], w4.z, acc);
    acc = fmaf(in_row[d + 3], w4.w, acc);
  }
  vals[e] = acc;
  __syncthreads();

  // per-head softmax over the 32 features of this thread's head
  const int h = e >> 5;
  const int base = h * EE;
  float mx = -1e30f;
#pragma unroll
  for (int k = 0; k < EE; ++k) mx = fmaxf(mx, vals[base + k]);
  const float ex = __expf(acc - mx);
  exps[e] = ex;
  __syncthreads();
  float sum = 0.f;
#pragma unroll
  for (int k = 0; k < EE; ++k) sum += exps[base + k];
  const float x = ex / sum;

  const int b = row / SS, s = row - b * SS;
  const int ee = e & 31;
  xs_out[(((b * HH + h) * SS) + s) * EE + ee] = x;
}

// ---------------------------------------------------------------------------
// K2: per (bh, i): scores[j] = (E*E + sum_{e1,e2} k(xi[e1], xj[e2])) / E,
//     attn = softmax_j(scores), y_row = sum_j attn[j] * x[bh][j][:].
// One block per (bh, i), 128 threads; thread t owns j=t.
// k(u,v) = u*v + m*(0.5*u*v - m*m/6), m=min(u,v); the plain u*v term sums
// to (sum_u)(sum_v) and is factored out of the 32x32 loop.
// ---------------------------------------------------------------------------
__global__ __launch_bounds__(128) void spline_k2(
    const float* __restrict__ xs_g,  // (B*H, S, E)
    float* __restrict__ y)           // (B, S, D)  y[b][i][h*E+e]
{
  const int bh = blockIdx.x >> 7;    // / 128
  const int i = blockIdx.x & 127;
  const int t = threadIdx.x;         // 0..127 == j

  __shared__ float xs[SS * EE];      // 16 KB
  __shared__ float sc[SS];
  __shared__ float at[SS];

  const float* src = xs_g + bh * SS * EE;
  for (int idx = t; idx < SS * EE; idx += 128) xs[idx] = src[idx];
  __syncthreads();

  // Own value row -> registers. Rotated SOURCE index (values are summed over,
  // order irrelevant); destination index k is compile-time -> stays in VGPRs.
  // Bank: (t*32 + (k+t)&31) % 32 = (k+t)%32 -> 2 lanes/bank = conflict-free.
  float vrow[EE];
  float sv = 0.f;
#pragma unroll
  for (int k = 0; k < EE; ++k) {
    vrow[k] = xs[t * EE + ((k + t) & 31)];
    sv += vrow[k];
  }

  float acc = 0.f;
  float su = 0.f;
  for (int e1 = 0; e1 < EE; ++e1) {
    const float u = xs[i * EE + e1];  // broadcast read
    su += u;
#pragma unroll
    for (int e2 = 0; e2 < EE; ++e2) {
      const float v = vrow[e2];
      const float m = fminf(u, v);
      const float p = u * v;
      const float m2 = m * m;
      const float s = fmaf(0.5f, p, m2 * (-1.0f / 6.0f));
      acc = fmaf(m, s, acc);
    }
  }
  const float logit = (fmaf(su, sv, acc) + (float)(EE * EE)) * (1.0f / (float)EE);

  sc[t] = logit;
  __syncthreads();
  float mx = -1e30f;
  for (int j = 0; j < SS; ++j) mx = fmaxf(mx, sc[j]);
  at[t] = __expf(logit - mx);
  __syncthreads();
  float sum = 0.f;
  for (int j = 0; j < SS; ++j) sum += at[j];

  // PV: threads 0..31 each own output feature e
  if (t < EE) {
    float o = 0.f;
    for (int j = 0; j < SS; ++j) o = fmaf(at[j], xs[j * EE + t], o);
    o /= sum;
    const int b = bh >> 3, h = bh & 7;
    y[(b * SS + i) * DD + h * EE + t] = o;
  }
}

// ---------------------------------------------------------------------------
// K3: out = y @ w_out^T + b_out. Same structure as K1, no softmax.
// ---------------------------------------------------------------------------
__global__ __launch_bounds__(256) void spline_k3(
    const float* __restrict__ y,      // (B,S,D)
    const float* __restrict__ w_out,  // (D,D)
    const float* __restrict__ b_out,  // (D,)
    float* __restrict__ out)          // (B,S,D)
{
  const int row = blockIdx.x;
  const int e = threadIdx.x;
  __shared__ float yr[DD];
  yr[e] = y[row * DD + e];
  __syncthreads();

  const float* wr = w_out + e * DD;
  float acc = b_out[e];
#pragma unroll 8
  for (int d = 0; d < DD; d += 4) {
    const float4 w4 = *reinterpret_cast<const float4*>(wr + d);
    acc = fmaf(yr[d + 0], w4.x, acc);
    acc = fmaf(yr[d + 1], w4.y, acc);
    acc = fmaf(yr[d + 2], w4.z, acc);
    acc = fmaf(yr[d + 3], w4.w, acc);
  }
  out[row * DD + e] = acc;
}

extern "C" void kernel_launch(void* const* d_in, const int* in_sizes, int n_in,
                              void* d_out, int out_size, void* d_ws, size_t ws_size,
                              hipStream_t stream) {
  const float* inp   = (const float*)d_in[0];  // (2,128,256)
  const float* w_in  = (const float*)d_in[1];  // (256,256)
  const float* b_in  = (const float*)d_in[2];  // (256,)
  const float* w_out = (const float*)d_in[3];  // (256,256)
  const float* b_out = (const float*)d_in[4];  // (256,)
  float* out = (float*)d_out;                  // (2,128,256)

  float* ws1 = (float*)d_ws;                   // x: (16,128,32) = 64K floats
  float* ws2 = ws1 + BB * HH * SS * EE;        // y: (2,128,256) = 64K floats

  spline_k1<<<BB * SS, 256, 0, stream>>>(inp, w_in, b_in, ws1);
  spline_k2<<<BB * HH * SS, 128, 0, stream>>>(ws1, ws2);
  spline_k3<<<BB * SS, 256, 0, stream>>>(ws2, w_out, b_out, out);
}

// Round 2
// 103.397 us; speedup vs baseline: 1.0491x; 1.0491x over previous
//
#include <hip/hip_runtime.h>
#include <math.h>

// Problem constants (Spline_Fitting): B=2, S=128, D=256, H=8, E=32
constexpr int BB = 2;
constexpr int SS = 128;
constexpr int DD = 256;
constexpr int HH = 8;
constexpr int EE = 32;

// ---------------------------------------------------------------------------
// K1: x[bh][s][e] = softmax_over_E( inputs @ w_in^T + b_in ), split per head.
// One block per (b,s) row. 256 threads, thread e computes output feature e.
// ---------------------------------------------------------------------------
__global__ __launch_bounds__(256) void spline_k1(
    const float* __restrict__ inp,   // (B,S,D)
    const float* __restrict__ w_in,  // (D,D)
    const float* __restrict__ b_in,  // (D,)
    float* __restrict__ xs_out)      // (B*H, S, E)
{
  const int row = blockIdx.x;        // b*S + s
  const int e = threadIdx.x;         // 0..255
  __shared__ float in_row[DD];
  __shared__ float vals[DD];
  __shared__ float exps[DD];

  in_row[e] = inp[row * DD + e];
  __syncthreads();

  const float* wr = w_in + e * DD;
  float acc = b_in[e];
#pragma unroll 8
  for (int d = 0; d < DD; d += 4) {
    const float4 w4 = *reinterpret_cast<const float4*>(wr + d);
    acc = fmaf(in_row[d + 0], w4.x, acc);
    acc = fmaf(in_row[d + 1], w4.y, acc);
    acc = fmaf(in_row[d + 2], w4.z, acc);
    acc = fmaf(in_row[d + 3], w4.w, acc);
  }
  vals[e] = acc;
  __syncthreads();

  const int h = e >> 5;
  const int base = h * EE;
  float mx = -1e30f;
#pragma unroll
  for (int k = 0; k < EE; ++k) mx = fmaxf(mx, vals[base + k]);
  const float ex = __expf(acc - mx);
  exps[e] = ex;
  __syncthreads();
  float sum = 0.f;
#pragma unroll
  for (int k = 0; k < EE; ++k) sum += exps[base + k];
  const float x = ex / sum;

  const int b = row / SS, s = row - b * SS;
  const int ee = e & 31;
  xs_out[(((b * HH + h) * SS) + s) * EE + ee] = x;
}

// ---------------------------------------------------------------------------
// K2a: symmetric score computation. scores[i][j] == scores[j][i], so compute
// only j >= i and mirror. Block p in [0,64] packs rows i=p (128-p pairs) and
// i=128-p (p pairs) into exactly 128 threads (p=0, p=64 are remainders).
// Per eval (5 VALU ops): acc += m*(u*v - m*m/3), m=min(u,v); total*0.5 and
// the factored (sum_u)(sum_v) term applied once per pair.
// ---------------------------------------------------------------------------
__global__ __launch_bounds__(128) void spline_k2a(
    const float* __restrict__ xs_g,  // (16,128,32)
    float* __restrict__ sc_g)        // (16,128,128)
{
  const int p = blockIdx.x;          // 0..64
  const int bh = blockIdx.y;         // 0..15
  const int t = threadIdx.x;         // 0..127

  __shared__ float xs[SS * EE];      // 16 KB
  const float4* s4 = (const float4*)(xs_g + bh * SS * EE);
  float4* x4 = (float4*)xs;
#pragma unroll
  for (int k = 0; k < 8; ++k) x4[t + 128 * k] = s4[t + 128 * k];
  __syncthreads();

  int i, j;
  bool active = true;
  if (p == 0) { i = 0; j = t; }
  else if (p == 64) {
    if (t < 64) { i = 64; j = 64 + t; } else { i = 0; j = 0; active = false; }
  } else {
    if (t >= p) { i = p; j = t; }
    else        { i = 128 - p; j = 128 - p + t; }
  }

  // Own value row -> registers (rotated source index: sum order irrelevant;
  // bank = (k+t)&31 -> 2 lanes/bank across wave64 = conflict-free).
  float vrow[EE];
  float sv = 0.f;
#pragma unroll
  for (int k = 0; k < EE; ++k) {
    vrow[k] = xs[j * EE + ((k + t) & 31)];
    sv += vrow[k];
  }

  float a0 = 0.f, a1 = 0.f, a2 = 0.f, a3 = 0.f, su = 0.f;
  const int ibase = i * EE;
#pragma unroll 4
  for (int e1 = 0; e1 < EE; ++e1) {
    const float u = xs[ibase + e1];  // <=2 distinct addrs per wave: broadcast
    su += u;
#pragma unroll
    for (int e2 = 0; e2 < EE; e2 += 4) {
      { const float v = vrow[e2 + 0], m = fminf(u, v), pm = u * v, w = m * m;
        const float q2 = fmaf(w, -(1.f / 3.f), pm); a0 = fmaf(m, q2, a0); }
      { const float v = vrow[e2 + 1], m = fminf(u, v), pm = u * v, w = m * m;
        const float q2 = fmaf(w, -(1.f / 3.f), pm); a1 = fmaf(m, q2, a1); }
      { const float v = vrow[e2 + 2], m = fminf(u, v), pm = u * v, w = m * m;
        const float q2 = fmaf(w, -(1.f / 3.f), pm); a2 = fmaf(m, q2, a2); }
      { const float v = vrow[e2 + 3], m = fminf(u, v), pm = u * v, w = m * m;
        const float q2 = fmaf(w, -(1.f / 3.f), pm); a3 = fmaf(m, q2, a3); }
    }
  }
  const float mins = 0.5f * ((a0 + a1) + (a2 + a3));
  const float logit = (fmaf(su, sv, mins) + (float)(EE * EE)) * (1.0f / (float)EE);

  if (active) {
    float* base = sc_g + bh * SS * SS;
    base[i * SS + j] = logit;
    if (i != j) base[j * SS + i] = logit;
  }
}

// ---------------------------------------------------------------------------
// K2b: attn = softmax_j(scores[i][:]), y_row = sum_j attn[j]*x[j][:].
// Block per (i, bh), 128 threads. Wave shuffle reductions for max/sum;
// PV split 4-ways over j, combined via LDS.
// ---------------------------------------------------------------------------
__global__ __launch_bounds__(128) void spline_k2b(
    const float* __restrict__ sc_g,  // (16,128,128)
    const float* __restrict__ xs_g,  // (16,128,32)
    float* __restrict__ y)           // (B,S,D)
{
  const int i = blockIdx.x;          // 0..127
  const int bh = blockIdx.y;         // 0..15
  const int t = threadIdx.x;         // 0..127

  __shared__ float xs[SS * EE];      // 16 KB
  __shared__ float at[SS];
  __shared__ float part[128];
  __shared__ float wred[4];

  const float4* s4 = (const float4*)(xs_g + bh * SS * EE);
  float4* x4 = (float4*)xs;
#pragma unroll
  for (int k = 0; k < 8; ++k) x4[t + 128 * k] = s4[t + 128 * k];

  const float logit = sc_g[(bh * SS + i) * SS + t];

  // block max over the 128 logits
  float mx = logit;
#pragma unroll
  for (int off = 32; off; off >>= 1) mx = fmaxf(mx, __shfl_xor(mx, off));
  const int wid = t >> 6;
  if ((t & 63) == 0) wred[wid] = mx;
  __syncthreads();
  mx = fmaxf(wred[0], wred[1]);

  const float ex = __expf(logit - mx);
  float sm = ex;
#pragma unroll
  for (int off = 32; off; off >>= 1) sm += __shfl_xor(sm, off);
  __syncthreads();               // wred reuse hazard
  if ((t & 63) == 0) wred[2 + wid] = sm;
  at[t] = ex;
  __syncthreads();
  const float rs = 1.0f / (wred[2] + wred[3]);

  // PV: feature e = t&31, j-quarter q = t>>5
  const int e = t & 31, q = t >> 5;
  float o = 0.f;
#pragma unroll
  for (int jj = 0; jj < 32; ++jj) {
    const int j = q * 32 + jj;
    o = fmaf(at[j], xs[j * EE + e], o);  // bank = e -> 2-way across wave: free
  }
  part[t] = o;
  __syncthreads();
  if (t < 32) {
    const float oo = (part[t] + part[t + 32] + part[t + 64] + part[t + 96]) * rs;
    const int b = bh >> 3, h = bh & 7;
    y[(b * SS + i) * DD + h * EE + t] = oo;
  }
}

// ---------------------------------------------------------------------------
// K3: out = y @ w_out^T + b_out.
// ---------------------------------------------------------------------------
__global__ __launch_bounds__(256) void spline_k3(
    const float* __restrict__ y,      // (B,S,D)
    const float* __restrict__ w_out,  // (D,D)
    const float* __restrict__ b_out,  // (D,)
    float* __restrict__ out)          // (B,S,D)
{
  const int row = blockIdx.x;
  const int e = threadIdx.x;
  __shared__ float yr[DD];
  yr[e] = y[row * DD + e];
  __syncthreads();

  const float* wr = w_out + e * DD;
  float acc = b_out[e];
#pragma unroll 8
  for (int d = 0; d < DD; d += 4) {
    const float4 w4 = *reinterpret_cast<const float4*>(wr + d);
    acc = fmaf(yr[d + 0], w4.x, acc);
    acc = fmaf(yr[d + 1], w4.y, acc);
    acc = fmaf(yr[d + 2], w4.z, acc);
    acc = fmaf(yr[d + 3], w4.w, acc);
  }
  out[row * DD + e] = acc;
}

extern "C" void kernel_launch(void* const* d_in, const int* in_sizes, int n_in,
                              void* d_out, int out_size, void* d_ws, size_t ws_size,
                              hipStream_t stream) {
  const float* inp   = (const float*)d_in[0];  // (2,128,256)
  const float* w_in  = (const float*)d_in[1];  // (256,256)
  const float* b_in  = (const float*)d_in[2];  // (256,)
  const float* w_out = (const float*)d_in[3];  // (256,256)
  const float* b_out = (const float*)d_in[4];  // (256,)
  float* out = (float*)d_out;                  // (2,128,256)

  float* ws_x  = (float*)d_ws;                         // (16,128,32)
  float* ws_sc = ws_x + BB * HH * SS * EE;             // (16,128,128)
  float* ws_y  = ws_sc + BB * HH * SS * SS;            // (2,128,256)

  spline_k1<<<BB * SS, 256, 0, stream>>>(inp, w_in, b_in, ws_x);
  spline_k2a<<<dim3(65, BB * HH), 128, 0, stream>>>(ws_x, ws_sc);
  spline_k2b<<<dim3(SS, BB * HH), 128, 0, stream>>>(ws_sc, ws_x, ws_y);
  spline_k3<<<BB * SS, 256, 0, stream>>>(ws_y, w_out, b_out, out);
}

// Round 4
// 91.883 us; speedup vs baseline: 1.1806x; 1.1253x over previous
//
#include <hip/hip_runtime.h>
#include <math.h>

// Problem constants (Spline_Fitting): B=2, S=128, D=256, H=8, E=32
constexpr int BB = 2;
constexpr int SS = 128;
constexpr int DD = 256;
constexpr int HH = 8;
constexpr int EE = 32;
constexpr int PKG = 132;  // per-row package: 32 sorted + 33 P1 + 33 P2 + 33 P3 (131, pad to 132)

// ---------------------------------------------------------------------------
// KA: x[bh][s][e] = softmax_E(inp @ w_in^T + b_in)  (as before), PLUS per-row
// sorted values + inclusive prefix sums of (s, s^2, s^3) -> pkg.
// Sort: 32-lane bitonic via __shfl_xor; scans: Hillis-Steele via __shfl_up.
// ---------------------------------------------------------------------------
__global__ __launch_bounds__(256) void spline_ka(
    const float* __restrict__ inp,   // (B,S,D)
    const float* __restrict__ w_in,  // (D,D)
    const float* __restrict__ b_in,  // (D,)
    float* __restrict__ xs_out,      // (16,128,32)
    float* __restrict__ pkg_g)       // (16,128,PKG)
{
  const int row = blockIdx.x;        // b*S + s
  const int e = threadIdx.x;         // 0..255
  __shared__ float in_row[DD];
  __shared__ float vals[DD];
  __shared__ float exps[DD];

  in_row[e] = inp[row * DD + e];
  __syncthreads();

  const float* wr = w_in + e * DD;
  float acc = b_in[e];
#pragma unroll 8
  for (int d = 0; d < DD; d += 4) {
    const float4 w4 = *reinterpret_cast<const float4*>(wr + d);
    acc = fmaf(in_row[d + 0], w4.x, acc);
    acc = fmaf(in_row[d + 1], w4.y, acc);
    acc = fmaf(in_row[d + 2], w4.z, acc);
    acc = fmaf(in_row[d + 3], w4.w, acc);
  }
  vals[e] = acc;
  __syncthreads();

  const int h = e >> 5, base = h * EE, l = e & 31;
  float mx = -1e30f;
#pragma unroll
  for (int k = 0; k < EE; ++k) mx = fmaxf(mx, vals[base + k]);
  const float ex = __expf(acc - mx);
  exps[e] = ex;
  __syncthreads();
  float sum = 0.f;
#pragma unroll
  for (int k = 0; k < EE; ++k) sum += exps[base + k];
  const float x = ex / sum;

  const int b = row >> 7, s = row & 127;
  const int bh = b * HH + h;
  xs_out[(bh * SS + s) * EE + l] = x;

  // ---- bitonic sort ascending across the 32-lane group ----
  float v = x;
#pragma unroll
  for (int k = 2; k <= 32; k <<= 1) {
#pragma unroll
    for (int j = k >> 1; j > 0; j >>= 1) {
      const float o = __shfl_xor(v, j, 32);
      const bool up = ((l & k) == 0);
      const bool tmin = (((l & j) == 0) == up);
      v = tmin ? fminf(v, o) : fmaxf(v, o);
    }
  }
  // ---- inclusive scans of v, v^2, v^3 ----
  float i1 = v, i2 = v * v, i3 = v * v * v;
#pragma unroll
  for (int j = 1; j < 32; j <<= 1) {
    const float o1 = __shfl_up(i1, j, 32);
    const float o2 = __shfl_up(i2, j, 32);
    const float o3 = __shfl_up(i3, j, 32);
    if (l >= j) { i1 += o1; i2 += o2; i3 += o3; }
  }
  float* pk = pkg_g + (bh * SS + s) * PKG;
  pk[l] = v;              // sorted values s[0..31]
  pk[32 + l + 1] = i1;    // P1[1..32]
  pk[65 + l + 1] = i2;    // P2[1..32]
  pk[98 + l + 1] = i3;    // P3[1..32]
  if (l == 0) { pk[32] = 0.f; pk[65] = 0.f; pk[98] = 0.f; }
}

// ---------------------------------------------------------------------------
// KB: fused scores + softmax + PV. Block = (bh, i), 128 threads, thread t = j.
// score(i,j) = (E^2 + T1_i*sv_j + Sum_b F(v_b, rowI_pkg)) / E with
// F(v) = 0.5*v*P2[idx] + 0.5*v^2*(T1-P1[idx]) + v^3*(idx-32)/6 - P3[idx]/6,
// idx = #{u in row i : u <= v} via branchless binary search in LDS.
// Own row j lives in registers (static indexing). Then block softmax + PV.
// ---------------------------------------------------------------------------
__global__ __launch_bounds__(128) void spline_kb(
    const float* __restrict__ xs_g,   // (16,128,32)
    const float* __restrict__ pkg_g,  // (16,128,PKG)
    float* __restrict__ y)            // (B,S,D)
{
  const int i = blockIdx.x;           // 0..127
  const int bh = blockIdx.y;          // 0..15
  const int t = threadIdx.x;          // 0..127 == j

  __shared__ float xs[SS * EE];       // 16 KB (for PV)
  __shared__ float pkv[131];          // row-i package
  __shared__ float at[SS];
  __shared__ float part[128];
  __shared__ float wred[4];

  // stage xs (coalesced, conflict-free)
  const float4* s4 = (const float4*)(xs_g + bh * SS * EE);
  float4* x4 = (float4*)xs;
#pragma unroll
  for (int k = 0; k < 8; ++k) x4[t + 128 * k] = s4[t + 128 * k];
  // stage row-i package
  const float* pk = pkg_g + (bh * SS + i) * PKG;
  if (t < 131) pkv[t] = pk[t];
  // own row -> registers (global is L2-resident; static indices only)
  float vreg[EE];
  {
    const float4* vr4 = (const float4*)(xs_g + (bh * SS + t) * EE);
    float4* vv = (float4*)vreg;
#pragma unroll
    for (int k = 0; k < 8; ++k) vv[k] = vr4[k];
  }
  __syncthreads();

  const float* sI = pkv;        // [32] sorted row i
  const float* P1 = pkv + 32;   // [33]
  const float* P2 = pkv + 65;   // [33]
  const float* P3 = pkv + 98;   // [33]
  const float T1 = P1[32];      // sum of row i (~1.0, softmax)

  float A = 0.f, B = 0.f, C = 0.f, Dg = 0.f, sv = 0.f;
#pragma unroll
  for (int bb = 0; bb < EE; ++bb) {
    const float v = vreg[bb];
    sv += v;
    int idx = 0;
#pragma unroll
    for (int off = 16; off > 0; off >>= 1)
      if (sI[idx + off - 1] <= v) idx += off;   // probe tree: broadcast banks
    if (sI[idx] <= v) ++idx;                    // idx in [0,32]
    const float g1 = P1[idx], g2 = P2[idx], g3 = P3[idx];
    const float v2 = v * v;
    const float fi = (float)idx - 32.0f;
    A = fmaf(v, g2, A);            // v * P2[idx]
    B = fmaf(v2, T1 - g1, B);      // v^2 * (T1 - P1[idx])
    C = fmaf(v2 * v, fi, C);       // v^3 * (idx - 32)
    Dg += g3;                      // P3[idx]
  }
  const float sumF = fmaf(0.5f, A + B, (C - Dg) * (1.f / 6.f));
  const float logit = (fmaf(T1, sv, sumF) + (float)(EE * EE)) * (1.0f / (float)EE);

  // ---- block softmax over 128 logits ----
  float mx = logit;
#pragma unroll
  for (int off = 32; off; off >>= 1) mx = fmaxf(mx, __shfl_xor(mx, off));
  const int wid = t >> 6;
  if ((t & 63) == 0) wred[wid] = mx;
  __syncthreads();
  mx = fmaxf(wred[0], wred[1]);

  const float ex = __expf(logit - mx);
  float sm = ex;
#pragma unroll
  for (int off = 32; off; off >>= 1) sm += __shfl_xor(sm, off);
  __syncthreads();
  if ((t & 63) == 0) wred[2 + wid] = sm;
  at[t] = ex;
  __syncthreads();
  const float rs = 1.0f / (wred[2] + wred[3]);

  // ---- PV: feature e = t&31, j-quarter q = t>>5 ----
  const int e = t & 31, q = t >> 5;
  float o = 0.f;
#pragma unroll
  for (int jj = 0; jj < 32; ++jj) {
    const int j = q * 32 + jj;
    o = fmaf(at[j], xs[j * EE + e], o);  // bank = e -> 2-way across wave: free
  }
  part[t] = o;
  __syncthreads();
  if (t < EE) {
    const float oo = (part[t] + part[t + 32] + part[t + 64] + part[t + 96]) * rs;
    const int b = bh >> 3, h = bh & 7;
    y[(b * SS + i) * DD + h * EE + t] = oo;
  }
}

// ---------------------------------------------------------------------------
// K3: out = y @ w_out^T + b_out.
// ---------------------------------------------------------------------------
__global__ __launch_bounds__(256) void spline_k3(
    const float* __restrict__ y,      // (B,S,D)
    const float* __restrict__ w_out,  // (D,D)
    const float* __restrict__ b_out,  // (D,)
    float* __restrict__ out)          // (B,S,D)
{
  const int row = blockIdx.x;
  const int e = threadIdx.x;
  __shared__ float yr[DD];
  yr[e] = y[row * DD + e];
  __syncthreads();

  const float* wr = w_out + e * DD;
  float acc = b_out[e];
#pragma unroll 8
  for (int d = 0; d < DD; d += 4) {
    const float4 w4 = *reinterpret_cast<const float4*>(wr + d);
    acc = fmaf(yr[d + 0], w4.x, acc);
    acc = fmaf(yr[d + 1], w4.y, acc);
    acc = fmaf(yr[d + 2], w4.z, acc);
    acc = fmaf(yr[d + 3], w4.w, acc);
  }
  out[row * DD + e] = acc;
}

extern "C" void kernel_launch(void* const* d_in, const int* in_sizes, int n_in,
                              void* d_out, int out_size, void* d_ws, size_t ws_size,
                              hipStream_t stream) {
  const float* inp   = (const float*)d_in[0];  // (2,128,256)
  const float* w_in  = (const float*)d_in[1];  // (256,256)
  const float* b_in  = (const float*)d_in[2];  // (256,)
  const float* w_out = (const float*)d_in[3];  // (256,256)
  const float* b_out = (const float*)d_in[4];  // (256,)
  float* out = (float*)d_out;                  // (2,128,256)

  float* ws_x   = (float*)d_ws;                        // (16,128,32)   65536
  float* ws_pkg = ws_x + BB * HH * SS * EE;            // (16,128,132) 270336
  float* ws_y   = ws_pkg + BB * HH * SS * PKG;         // (2,128,256)   65536

  spline_ka<<<BB * SS, 256, 0, stream>>>(inp, w_in, b_in, ws_x, ws_pkg);
  spline_kb<<<dim3(SS, BB * HH), 128, 0, stream>>>(ws_x, ws_pkg, ws_y);
  spline_k3<<<BB * SS, 256, 0, stream>>>(ws_y, w_out, b_out, out);
}